// Round 12
// baseline (110.575 us; speedup 1.0000x reference)
//
#include <hip/hip_runtime.h>
#include <cstddef>
#include <cstdint>

#define NN 4096          // spatial n = 64*64
#define CIN 256          // input channels
#define CQKV 768         // qkv output channels
#define NBATCH 16
#define QSCALE 0.17677669529663687f  // 32^-0.5

typedef short s16x8 __attribute__((ext_vector_type(8)));
typedef float f32x4 __attribute__((ext_vector_type(4)));

__device__ __forceinline__ float bf2f(unsigned short u) {
    unsigned int x = ((unsigned int)u) << 16;
    return __builtin_bit_cast(float, x);
}
__device__ __forceinline__ unsigned short f2bf(float f) {
    unsigned int u = __builtin_bit_cast(unsigned int, f);
    return (unsigned short)((u + 0x7fffu + ((u >> 16) & 1u)) >> 16);   // RNE
}
__device__ __forceinline__ void glds16(const void* gsrc, void* lds) {
    __builtin_amdgcn_global_load_lds(
        (const __attribute__((address_space(1))) unsigned int*)gsrc,
        (__attribute__((address_space(3))) unsigned int*)lds,
        16, 0, 0);
}

// ---------------------------------------------------------------------------
// K0a: x [b][256][4096] f32  ->  xT [b][4096][256] bf16   (transpose + cast)
// ---------------------------------------------------------------------------
__global__ __launch_bounds__(256)
void xpose(const float* __restrict__ x, unsigned short* __restrict__ xT)
{
    const int b = blockIdx.z;
    const int n0 = blockIdx.x * 64, c0 = blockIdx.y * 64;
    __shared__ float xs[64][65];
    const int t = threadIdx.x;
    const float* xb = x + (size_t)b * CIN * NN;
#pragma unroll
    for (int p = 0; p < 4; ++p) {
        const int row = p * 16 + (t >> 4);
        const int col = (t & 15) * 4;
        const float4 v = *reinterpret_cast<const float4*>(
            &xb[(size_t)(c0 + row) * NN + n0 + col]);
        xs[col + 0][row] = v.x; xs[col + 1][row] = v.y;
        xs[col + 2][row] = v.z; xs[col + 3][row] = v.w;
    }
    __syncthreads();
    const int n = t >> 2, cch = (t & 3) * 16;
    unsigned short arr[16];
#pragma unroll
    for (int e = 0; e < 16; ++e) arr[e] = f2bf(xs[n][cch + e]);
    unsigned short* dst = xT + ((size_t)b * NN + n0 + n) * 256 + c0 + cch;
    *reinterpret_cast<s16x8*>(&dst[0]) = *reinterpret_cast<s16x8*>(&arr[0]);
    *reinterpret_cast<s16x8*>(&dst[8]) = *reinterpret_cast<s16x8*>(&arr[8]);
}

// ---------------------------------------------------------------------------
// K0b: w_qkv f32 -> bf16 with kv-row reordering:
//   wb2 rows [0,256)             = w rows [0,256)              (q, unchanged)
//   wb2 rows [256+g*256, +128)   = w rows [256+g*128, +128)    (k group g)
//   wb2 rows [256+g*256+128, +128) = w rows [512+g*128, +128)  (v group g)
// ---------------------------------------------------------------------------
__global__ __launch_bounds__(256)
void wcvt2(const float* __restrict__ w, unsigned short* __restrict__ wb2)
{
    const int i = (blockIdx.x * 256 + threadIdx.x) * 4;   // elem idx in wb2
    const int row = i >> 8, col = i & 255;
    int orow;
    if (row < 256) orow = row;
    else {
        const int g = (row - 256) >> 8;
        const int within = (row - 256) & 255;
        const int half = within >> 7;          // 0=k, 1=v
        const int idx = within & 127;
        orow = 256 + half * 256 + g * 128 + idx;
    }
    const float4 v = *reinterpret_cast<const float4*>(&w[(size_t)orow * 256 + col]);
    unsigned short a[4] = { f2bf(v.x), f2bf(v.y), f2bf(v.z), f2bf(v.w) };
    *reinterpret_cast<ushort2*>(&wb2[i])     = *reinterpret_cast<ushort2*>(&a[0]);
    *reinterpret_cast<ushort2*>(&wb2[i + 2]) = *reinterpret_cast<ushort2*>(&a[2]);
}

// ---------------------------------------------------------------------------
// gemm_asym<MF,NF>: (MF*32) x (NF*32) x K256 tile, BK=32, 3-buffer
// counted-vmcnt pipeline (R9-proven schedule). A [MF*32][256], B [NF*32][256]
// both K-contiguous bf16, pre-offset. Per-wave 6 glds16/batch -> vmcnt(6).
// Stage sizes: A = MF*2048 B, B = NF*2048 B (32 rows/frag x 64 B rows).
// LDS: A 3 x MF*2048 at 0; B 3 x NF*2048 after. Total 3*(MF+NF)*2048.
// Swizzle: chunk ^ ((row>>1)&3) both sides (2-way, free).
// Wave grid: wr = (w>>1)*(MF*16), wc = (w&1)*(NF*16).
// ---------------------------------------------------------------------------
template<int MF, int NF>
__device__ __forceinline__ void gemm_asym(const unsigned short* __restrict__ Ab,
                                          const unsigned short* __restrict__ Bb,
                                          char* __restrict__ smem,
                                          f32x4 (&acc)[MF][NF])
{
    constexpr int AW = MF / 2;     // A glds16 per wave per batch
    constexpr int BW = NF / 2;
    constexpr int ASTG = MF * 2048;   // bytes per A stage
    constexpr int BSTG = NF * 2048;   // bytes per B stage
    const int t = threadIdx.x;
    const int lane = t & 63, w = t >> 6;
    const int lr = lane & 15, lq = lane >> 4;
    const int wr = (w >> 1) * (MF * 16), wc = (w & 1) * (NF * 16);
    char* Abuf = smem;
    char* Bbuf = smem + 3 * ASTG;

#define STG_H(h)                                                               \
  { char* ab = Abuf + ((h) % 3) * ASTG;                                        \
    char* bb = Bbuf + ((h) % 3) * BSTG;                                        \
    _Pragma("unroll") for (int j = 0; j < AW; ++j) {                           \
        const int ch = (w * AW + j) * 64 + lane;                               \
        const int row = ch >> 2, c = (ch & 3) ^ ((row >> 1) & 3);              \
        glds16(Ab + (size_t)row * 256 + (h) * 32 + c * 8,                      \
               ab + (w * AW + j) * 1024); }                                    \
    _Pragma("unroll") for (int j = 0; j < BW; ++j) {                           \
        const int ch = (w * BW + j) * 64 + lane;                               \
        const int row = ch >> 2, c = (ch & 3) ^ ((row >> 1) & 3);              \
        glds16(Bb + (size_t)row * 256 + (h) * 32 + c * 8,                      \
               bb + (w * BW + j) * 1024); } }

#define CMP_H(h)                                                               \
  { char* ab = Abuf + ((h) % 3) * ASTG;                                        \
    char* bb = Bbuf + ((h) % 3) * BSTG;                                        \
    s16x8 af[MF], bfr[NF];                                                     \
    _Pragma("unroll") for (int m = 0; m < MF; ++m) {                           \
        const int row = wr + m * 16 + lr;                                      \
        af[m] = *(const s16x8*)(ab + row * 64 + ((lq ^ ((row >> 1) & 3)) << 4)); } \
    _Pragma("unroll") for (int nn = 0; nn < NF; ++nn) {                        \
        const int col = wc + nn * 16 + lr;                                     \
        bfr[nn] = *(const s16x8*)(bb + col * 64 + ((lq ^ ((col >> 1) & 3)) << 4)); } \
    __builtin_amdgcn_s_setprio(1);                                             \
    _Pragma("unroll") for (int m = 0; m < MF; ++m)                             \
    _Pragma("unroll") for (int nn = 0; nn < NF; ++nn)                          \
        acc[m][nn] = __builtin_amdgcn_mfma_f32_16x16x32_bf16(af[m], bfr[nn],   \
                                                             acc[m][nn], 0, 0, 0); \
    __builtin_amdgcn_s_setprio(0); }

    STG_H(0); STG_H(1);                // 12 load-instrs in flight per wave
#pragma unroll
    for (int i = 0; i < 8; ++i) {
        if (i < 7) asm volatile("s_waitcnt vmcnt(6)" ::: "memory");
        else       asm volatile("s_waitcnt vmcnt(0)" ::: "memory");
        __builtin_amdgcn_s_barrier();
        __builtin_amdgcn_sched_barrier(0);
        if (i < 6) STG_H(i + 2);
        CMP_H(i);
    }
#undef STG_H
#undef CMP_H
}

// ---------------------------------------------------------------------------
// K1 (fused): grid (32 n-tiles, 3 types, 16 batches), 72 KB LDS, 2 blocks/CU.
//  ty=0: q block, ONE 256x128 GEMM (all 8 heads) -> softmax-over-d -> qT
//  ty=1,2: kv group g, ONE 128x256 transposed GEMM (k cols 0-127, v 128-255)
//          -> exp/Z + split LDS transpose + ctx MFMA. k/v never touch HBM.
// ---------------------------------------------------------------------------
__global__ __launch_bounds__(256, 2)
void qkv_fused(const unsigned short* __restrict__ wb2,
               const unsigned short* __restrict__ xT,
               unsigned short* __restrict__ qT,
               float* __restrict__ ctx_part,
               float* __restrict__ z_part)
{
    __shared__ __align__(16) char smem[73728];
    const int nt = blockIdx.x;
    const int ty = blockIdx.y;
    const int b  = blockIdx.z;
    const int t = threadIdx.x;
    const int lane = t & 63, w = t >> 6;
    const int lr = lane & 15, lq = lane >> 4;
    const int n0 = nt * 128;
    const unsigned short* xslab = xT + ((size_t)b * NN + n0) * 256;

    if (ty == 0) {
        // ---------------- q block: 256 rows x 128 n ----------------
        const int wr = (w >> 1) * 128, wc = (w & 1) * 64;
        f32x4 acc[8][4] = {};
        gemm_asym<8, 4>(wb2, xslab, smem, acc);

        __syncthreads();    // staging LDS free -> qs [128 n][256 c] swizzled
#pragma unroll
        for (int nn = 0; nn < 4; ++nn) {
            const int col = wc + nn * 16 + lr;      // n index
            const int swz = (col & 7) << 4;
#pragma unroll
            for (int hp = 0; hp < 4; ++hp) {        // 4 heads per wave-half
                float mx = -1e30f;
#pragma unroll
                for (int u = 0; u < 2; ++u)
#pragma unroll
                    for (int r = 0; r < 4; ++r)
                        mx = fmaxf(mx, acc[hp * 2 + u][nn][r]);
                mx = fmaxf(mx, __shfl_xor(mx, 16));
                mx = fmaxf(mx, __shfl_xor(mx, 32));
                float er[2][4];
                float s = 0.f;
#pragma unroll
                for (int u = 0; u < 2; ++u)
#pragma unroll
                    for (int r = 0; r < 4; ++r) {
                        er[u][r] = __expf(acc[hp * 2 + u][nn][r] - mx);
                        s += er[u][r];
                    }
                s += __shfl_xor(s, 16);
                s += __shfl_xor(s, 32);
                const float inv = QSCALE / s;
#pragma unroll
                for (int u = 0; u < 2; ++u) {
                    ushort4 pk;
                    pk.x = f2bf(er[u][0] * inv);
                    pk.y = f2bf(er[u][1] * inv);
                    pk.z = f2bf(er[u][2] * inv);
                    pk.w = f2bf(er[u][3] * inv);
                    const int cbyte = (wr + hp * 32 + u * 16 + lq * 4) * 2;
                    *(ushort4*)(smem + ((col * 512 + cbyte) ^ swz)) = pk;
                }
            }
        }
        __syncthreads();
        // copy out full 256-c rows: qT[b][n0+nl][0..256)
        const int nl = t >> 1, half = t & 1;
        unsigned short* dst = qT + ((size_t)b * NN + n0 + nl) * 256 + half * 128;
        const int rswz = (nl & 7) << 4;
#pragma unroll
        for (int i = 0; i < 16; ++i) {
            const int boff = (nl * 512 + half * 256 + i * 16) ^ rswz;
            *(s16x8*)(dst + i * 8) = *(const s16x8*)(smem + boff);
        }
    } else {
        // ------------- kv block: 128 n x 256 (k|v) transposed -------------
        const int g = ty - 1;
        f32x4 acc[4][8] = {};
        gemm_asym<4, 8>(xslab, wb2 + (size_t)(256 + g * 256) * 256, smem, acc);

        // k waves (w&1==0, cols 0-127): rounded exp in place + Z partials
        if ((w & 1) == 0) {
            float zl[8];
#pragma unroll
            for (int nn = 0; nn < 8; ++nn) zl[nn] = 0.f;
#pragma unroll
            for (int m = 0; m < 4; ++m)
#pragma unroll
                for (int nn = 0; nn < 8; ++nn)
#pragma unroll
                    for (int r = 0; r < 4; ++r) {
                        const float e = bf2f(f2bf(__expf(acc[m][nn][r])));
                        acc[m][nn][r] = e;          // numerator = rounded value
                        zl[nn] += e;                // Z consistent with numerator
                    }
#pragma unroll
            for (int nn = 0; nn < 8; ++nn) {
                zl[nn] += __shfl_xor(zl[nn], 16);
                zl[nn] += __shfl_xor(zl[nn], 32);
            }
            float* zp = z_part + ((((size_t)(b * 32 + nt)) * 2 + g) * 2 + (w >> 1)) * 128;
            zp[lane]      = zl[lq];        // col = lq*16+lr = lane
            zp[64 + lane] = zl[4 + lq];    // col = 64 + lane
        }

        // split transpose + ctx MFMA (R9-proven layout), two n-halves
        __syncthreads();
        f32x4 cacc[2][2] = {};
#pragma unroll
        for (int p = 0; p < 2; ++p) {
            if ((w >> 1) == p) {
                char* base = (w & 1) ? (smem + 16384) : smem;   // v : ek
#pragma unroll
                for (int m = 0; m < 4; ++m)
#pragma unroll
                    for (int nn = 0; nn < 8; ++nn) {
                        const int col = nn * 16 + lr;           // k/v col 0..127
                        const int swz = (col & 7) << 4;
                        const int rowb = (m * 16 + lq * 4) * 2; // n-local byte
                        const unsigned int p0 = (unsigned int)f2bf(acc[m][nn][0])
                            | ((unsigned int)f2bf(acc[m][nn][1]) << 16);
                        const unsigned int p1 = (unsigned int)f2bf(acc[m][nn][2])
                            | ((unsigned int)f2bf(acc[m][nn][3]) << 16);
                        *(unsigned int*)(base + ((col * 128 + rowb) ^ swz))     = p0;
                        *(unsigned int*)(base + ((col * 128 + rowb + 4) ^ swz)) = p1;
                    }
            }
            __syncthreads();
#pragma unroll
            for (int ks2 = 0; ks2 < 2; ++ks2) {
                s16x8 afk[2], bfv[2];
#pragma unroll
                for (int dt = 0; dt < 2; ++dt) {
                    const int drow = w * 32 + dt * 16 + lr;
                    afk[dt] = *(const s16x8*)(smem + drow * 128 +
                        ((((ks2 * 4 + lq) ^ (drow & 7))) << 4));
                }
#pragma unroll
                for (int et = 0; et < 2; ++et) {
                    const int erow = w * 32 + et * 16 + lr;
                    bfv[et] = *(const s16x8*)(smem + 16384 + erow * 128 +
                        ((((ks2 * 4 + lq) ^ (erow & 7))) << 4));
                }
#pragma unroll
                for (int dt = 0; dt < 2; ++dt)
#pragma unroll
                    for (int et = 0; et < 2; ++et)
                        cacc[dt][et] = __builtin_amdgcn_mfma_f32_16x16x32_bf16(
                            afk[dt], bfv[et], cacc[dt][et], 0, 0, 0);
            }
            __syncthreads();
        }
        float* cp = ctx_part + ((((size_t)(b * 32 + nt)) * 2 + g) * 4 + w) * 1024;
#pragma unroll
        for (int dt = 0; dt < 2; ++dt)
#pragma unroll
            for (int et = 0; et < 2; ++et)
#pragma unroll
                for (int r = 0; r < 4; ++r)
                    cp[(dt * 16 + lq * 4 + r) * 32 + et * 16 + lr] = cacc[dt][et][r];
    }
}

// ---------------------------------------------------------------------------
// make_m: reduce 32 n-tile ctx partials + Z, fold w_out -> Mmat bf16
// ---------------------------------------------------------------------------
__global__ __launch_bounds__(256)
void make_m(const float* __restrict__ ctx_part, const float* __restrict__ z_part,
            const float* __restrict__ w_out, unsigned short* __restrict__ Mmat)
{
    const int h = blockIdx.x, b = blockIdx.y;
    const int g = h >> 2, hh = h & 3;
    const int t = threadIdx.x;
    __shared__ float ctx[32][33];
    __shared__ float zinv[32];

    for (int c = t; c < 1024; c += 256) {
        float s = 0.f;
#pragma unroll 8
        for (int nt = 0; nt < 32; ++nt)
            s += ctx_part[((((size_t)(b * 32 + nt)) * 2 + g) * 4 + hh) * 1024 + c];
        ctx[c >> 5][c & 31] = s;
    }
    if (t < 32) {
        float z = 0.f;
#pragma unroll 8
        for (int nt = 0; nt < 32; ++nt) {
            const size_t base = (((size_t)(b * 32 + nt)) * 2 + g) * 2;
            z += z_part[(base + 0) * 128 + hh * 32 + t];
            z += z_part[(base + 1) * 128 + hh * 32 + t];
        }
        zinv[t] = 1.f / z;
    }
    __syncthreads();

    const int o = t;
    float wrow[32];
#pragma unroll
    for (int e = 0; e < 32; ++e)
        wrow[e] = w_out[(size_t)o * 256 + h * 32 + e];
#pragma unroll 4
    for (int d = 0; d < 32; ++d) {
        float s = 0.f;
#pragma unroll
        for (int e = 0; e < 32; ++e)
            s = fmaf(wrow[e], ctx[d][e], s);
        Mmat[((size_t)b * 256 + o) * 256 + h * 32 + d] = f2bf(s * zinv[d]);
    }
}

// ---------------------------------------------------------------------------
// gemm_pipe3 (R9, unchanged): symmetric 128x128 3-buffer counted-vmcnt pipe.
// ---------------------------------------------------------------------------
__device__ __forceinline__ void gemm_pipe3(const unsigned short* __restrict__ Ab,
                                           const unsigned short* __restrict__ Bb,
                                           int m0, int n0, char* smem,
                                           f32x4 (&acc)[4][4])
{
    const int t = threadIdx.x;
    const int lane = t & 63, w = t >> 6;
    const int lr = lane & 15, lq = lane >> 4;
    const int wr = (w >> 1) * 64, wc = (w & 1) * 64;
    const int ch0 = (w * 2 + 0) * 64 + lane;
    const int ch1 = (w * 2 + 1) * 64 + lane;
    const int r0 = ch0 >> 2, c0s = (ch0 & 3) ^ ((r0 >> 1) & 3);
    const int r1 = ch1 >> 2, c1s = (ch1 & 3) ^ ((r1 >> 1) & 3);
    char* Abuf = smem;
    char* Bbuf = smem + 24576;

#define STG_H(h)                                                               \
  { char* ab = Abuf + ((h) % 3) * 8192;                                        \
    char* bb = Bbuf + ((h) % 3) * 8192;                                        \
    glds16(Ab + (size_t)(m0 + r0) * 256 + (h) * 32 + c0s * 8, ab + (w*2+0)*1024); \
    glds16(Ab + (size_t)(m0 + r1) * 256 + (h) * 32 + c1s * 8, ab + (w*2+1)*1024); \
    glds16(Bb + (size_t)(n0 + r0) * 256 + (h) * 32 + c0s * 8, bb + (w*2+0)*1024); \
    glds16(Bb + (size_t)(n0 + r1) * 256 + (h) * 32 + c1s * 8, bb + (w*2+1)*1024); }

#define CMP_H(h)                                                               \
  { char* ab = Abuf + ((h) % 3) * 8192;                                        \
    char* bb = Bbuf + ((h) % 3) * 8192;                                        \
    s16x8 af[4], bfr[4];                                                       \
    _Pragma("unroll") for (int m = 0; m < 4; ++m) {                            \
        const int row = wr + m * 16 + lr;                                      \
        af[m] = *(const s16x8*)(ab + row * 64 + ((lq ^ ((row >> 1) & 3)) << 4)); } \
    _Pragma("unroll") for (int n = 0; n < 4; ++n) {                            \
        const int col = wc + n * 16 + lr;                                      \
        bfr[n] = *(const s16x8*)(bb + col * 64 + ((lq ^ ((col >> 1) & 3)) << 4)); } \
    __builtin_amdgcn_s_setprio(1);                                             \
    _Pragma("unroll") for (int m = 0; m < 4; ++m)                              \
    _Pragma("unroll") for (int n = 0; n < 4; ++n)                              \
        acc[m][n] = __builtin_amdgcn_mfma_f32_16x16x32_bf16(af[m], bfr[n],     \
                                                            acc[m][n], 0, 0, 0); \
    __builtin_amdgcn_s_setprio(0); }

    STG_H(0); STG_H(1);
#pragma unroll
    for (int i = 0; i < 8; ++i) {
        if (i < 7) asm volatile("s_waitcnt vmcnt(4)" ::: "memory");
        else       asm volatile("s_waitcnt vmcnt(0)" ::: "memory");
        __builtin_amdgcn_s_barrier();
        __builtin_amdgcn_sched_barrier(0);
        if (i < 6) STG_H(i + 2);
        CMP_H(i);
    }
#undef STG_H
#undef CMP_H
}

// ---------------------------------------------------------------------------
// K5: out = Mmat @ q + bias (f32), R9-proven two-half transposed epilogue.
// ---------------------------------------------------------------------------
__global__ __launch_bounds__(256, 3)
void gemm_out(const unsigned short* __restrict__ Mmat,
              const unsigned short* __restrict__ qT,
              float* __restrict__ out, const float* __restrict__ bias)
{
    __shared__ __align__(16) char smem[49152];
    const int bz = blockIdx.z;
    const int m0 = blockIdx.y * 128, n0 = blockIdx.x * 128;
    const unsigned short* Ab = Mmat + (size_t)bz * 256 * 256;
    const unsigned short* Bb = qT + (size_t)bz * NN * 256;

    f32x4 acc[4][4] = {};
    gemm_pipe3(Ab, Bb, m0, n0, smem, acc);

    const int t = threadIdx.x;
    const int lane = t & 63, w = t >> 6;
    const int lr = lane & 15, lq = lane >> 4;
    const int wc = (w & 1) * 64;

    __syncthreads();
    float* Yb = out + (size_t)bz * CIN * NN;
#pragma unroll
    for (int hf = 0; hf < 2; ++hf) {
        if ((w >> 1) == hf) {
#pragma unroll
            for (int m = 0; m < 4; ++m)
#pragma unroll
                for (int r = 0; r < 4; ++r) {
                    const int rl = m * 16 + lq * 4 + r;
                    const float bv = bias[m0 + hf * 64 + rl];
                    const int rb = rl * 512;
                    const int xs = (rl & 7) << 4;
#pragma unroll
                    for (int n = 0; n < 4; ++n) {
                        const int col = wc + n * 16 + lr;
                        *(float*)(smem + rb + ((col * 4) ^ xs)) = acc[m][n][r] + bv;
                    }
                }
        }
        __syncthreads();
#pragma unroll
        for (int p = 0; p < 4; ++p) {
            const int rl = p * 16 + (t >> 4);
            const int rb = rl * 512;
            const int xs = (rl & 7) << 4;
            const int cb = (t & 15) * 32;
            const float4 v0 = *(const float4*)(smem + rb + ((cb + 0) ^ xs));
            const float4 v1 = *(const float4*)(smem + rb + ((cb + 16) ^ xs));
            float* dst = Yb + (size_t)(m0 + hf * 64 + rl) * NN + n0 + (t & 15) * 8;
            *(float4*)dst = v0;
            *(float4*)(dst + 4) = v1;
        }
        __syncthreads();
    }
}

// ---------------------------------------------------------------------------
extern "C" void kernel_launch(void* const* d_in, const int* in_sizes, int n_in,
                              void* d_out, int out_size, void* d_ws, size_t ws_size,
                              hipStream_t stream)
{
    const float* x     = (const float*)d_in[0];
    const float* w_qkv = (const float*)d_in[1];
    const float* w_out = (const float*)d_in[2];
    const float* b_out = (const float*)d_in[3];
    float* out = (float*)d_out;

    char* ws = (char*)d_ws;
    size_t off = 0;
    unsigned short* xT  = (unsigned short*)(ws + off);  off += (size_t)NBATCH * NN * CIN * 2;          // 32 MiB
    unsigned short* qT  = (unsigned short*)(ws + off);  off += (size_t)NBATCH * NN * CIN * 2;          // 32 MiB
    float* ctx_part     = (float*)(ws + off);           off += (size_t)NBATCH * 32 * 2 * 4 * 1024 * 4; // 16 MiB
    float* z_part       = (float*)(ws + off);           off += (size_t)NBATCH * 32 * 2 * 2 * 128 * 4;  // 1 MiB
    unsigned short* Mmat= (unsigned short*)(ws + off);  off += (size_t)NBATCH * 256 * 256 * 2;         // 2 MiB
    unsigned short* wb2 = (unsigned short*)(ws + off);  off += (size_t)CQKV * CIN * 2;

    // K0: transpose+cast x, cast+reorder w_qkv
    xpose<<<dim3(NN / 64, CIN / 64, NBATCH), 256, 0, stream>>>(x, xT);
    wcvt2<<<dim3(CQKV * CIN / 1024), 256, 0, stream>>>(w_qkv, wb2);

    // K1 (fused): q -> qT (softmax); k/v -> ctx/z partials, never touching HBM
    qkv_fused<<<dim3(32, 3, NBATCH), 256, 0, stream>>>(wb2, xT, qT, ctx_part, z_part);

    // K4: Mmat = fold(w_out, normalized context)
    make_m<<<dim3(8, NBATCH), 256, 0, stream>>>(ctx_part, z_part, w_out, Mmat);

    // K5: out = Mmat @ q + b_out
    gemm_out<<<dim3(32, 2, NBATCH), 256, 0, stream>>>(Mmat, qT, out, b_out);
}

// Round 13
// 103.232 us; speedup vs baseline: 1.0711x; 1.0711x over previous
//
#include <hip/hip_runtime.h>
#include <cstddef>
#include <cstdint>

#define NN 4096          // spatial n = 64*64
#define CIN 256          // input channels
#define CQKV 768         // qkv output channels
#define NBATCH 16
#define QSCALE 0.17677669529663687f  // 32^-0.5

typedef short s16x8 __attribute__((ext_vector_type(8)));
typedef float f32x4 __attribute__((ext_vector_type(4)));

__device__ __forceinline__ float bf2f(unsigned short u) {
    unsigned int x = ((unsigned int)u) << 16;
    return __builtin_bit_cast(float, x);
}
__device__ __forceinline__ unsigned short f2bf(float f) {
    unsigned int u = __builtin_bit_cast(unsigned int, f);
    return (unsigned short)((u + 0x7fffu + ((u >> 16) & 1u)) >> 16);   // RNE
}
__device__ __forceinline__ void glds16(const void* gsrc, void* lds) {
    __builtin_amdgcn_global_load_lds(
        (const __attribute__((address_space(1))) unsigned int*)gsrc,
        (__attribute__((address_space(3))) unsigned int*)lds,
        16, 0, 0);
}

// ---------------------------------------------------------------------------
// prep: merged K0a + K0b (one dispatch).
//  z < NBATCH : x [b][256][4096] f32 -> xT [b][4096][256] bf16 (transpose+cast)
//  z == NBATCH: w_qkv f32 -> wb bf16 (192 chunks over the (x,y) block space)
// ---------------------------------------------------------------------------
__global__ __launch_bounds__(256)
void prep(const float* __restrict__ x, unsigned short* __restrict__ xT,
          const float* __restrict__ w, unsigned short* __restrict__ wb)
{
    const int t = threadIdx.x;
    if (blockIdx.z < NBATCH) {
        const int b = blockIdx.z;
        const int n0 = blockIdx.x * 64, c0 = blockIdx.y * 64;
        __shared__ float xs[64][65];
        const float* xb = x + (size_t)b * CIN * NN;
#pragma unroll
        for (int p = 0; p < 4; ++p) {
            const int row = p * 16 + (t >> 4);
            const int col = (t & 15) * 4;
            const float4 v = *reinterpret_cast<const float4*>(
                &xb[(size_t)(c0 + row) * NN + n0 + col]);
            xs[col + 0][row] = v.x; xs[col + 1][row] = v.y;
            xs[col + 2][row] = v.z; xs[col + 3][row] = v.w;
        }
        __syncthreads();
        const int n = t >> 2, cch = (t & 3) * 16;
        unsigned short arr[16];
#pragma unroll
        for (int e = 0; e < 16; ++e) arr[e] = f2bf(xs[n][cch + e]);
        unsigned short* dst = xT + ((size_t)b * NN + n0 + n) * 256 + c0 + cch;
        *reinterpret_cast<s16x8*>(&dst[0]) = *reinterpret_cast<s16x8*>(&arr[0]);
        *reinterpret_cast<s16x8*>(&dst[8]) = *reinterpret_cast<s16x8*>(&arr[8]);
    } else {
        const int bid = blockIdx.y * 64 + blockIdx.x;
        if (bid < CQKV * CIN / 1024) {
            const int i = (bid * 256 + t) * 4;
            const float4 v = *reinterpret_cast<const float4*>(&w[i]);
            unsigned short a[4] = { f2bf(v.x), f2bf(v.y), f2bf(v.z), f2bf(v.w) };
            *reinterpret_cast<ushort2*>(&wb[i])     = *reinterpret_cast<ushort2*>(&a[0]);
            *reinterpret_cast<ushort2*>(&wb[i + 2]) = *reinterpret_cast<ushort2*>(&a[2]);
        }
    }
}

// ---------------------------------------------------------------------------
// BK=64 double-buffered 128x128 GEMM core (64 KB LDS) — R2/R6-verified.
// A [rows][256] bf16 row-major, BT [rows][256] bf16 (K-contiguous both).
// acc[m][nn][r]: out[row = wr+m*16+lq*4+r][col = wc+nn*16+lr].
// ---------------------------------------------------------------------------
__device__ __forceinline__ void gemm_core64(const unsigned short* __restrict__ Ab,
                                            const unsigned short* __restrict__ Bb,
                                            int m0, int n0, char* smem,
                                            f32x4 (&acc)[4][4])
{
    const int t = threadIdx.x;
    const int lane = t & 63, w = t >> 6;
    const int lr = lane & 15, lq = lane >> 4;
    const int wr = (w >> 1) * 64, wc = (w & 1) * 64;
    const int srow = t >> 3;
    const int schunk = (t & 7) ^ (srow & 7);
    const int wq = w << 10;
    const int xr = lr & 7;

    char* A0 = smem;          char* B0 = smem + 16384;
    char* A1 = smem + 32768;  char* B1 = smem + 49152;

#define STG(bufA, bufB, k0)                                                     \
    { _Pragma("unroll") for (int i = 0; i < 4; ++i)                             \
        glds16(Ab + (size_t)(m0 + i*32 + srow)*256 + (k0) + schunk*8,           \
               (bufA) + i*4096 + wq);                                           \
      _Pragma("unroll") for (int i = 0; i < 4; ++i)                             \
        glds16(Bb + (size_t)(n0 + i*32 + srow)*256 + (k0) + schunk*8,           \
               (bufB) + i*4096 + wq); }

#define CMP(bufA, bufB)                                                         \
    { s16x8 af[4][2], bfr[4][2];                                                \
      _Pragma("unroll") for (int m = 0; m < 4; ++m) {                           \
        const char* rp = (bufA) + (wr + m*16 + lr)*128;                         \
        af[m][0] = *(const s16x8*)(rp + (((0*4 + lq) ^ xr) << 4));              \
        af[m][1] = *(const s16x8*)(rp + (((1*4 + lq) ^ xr) << 4)); }            \
      _Pragma("unroll") for (int n = 0; n < 4; ++n) {                           \
        const char* rp = (bufB) + (wc + n*16 + lr)*128;                         \
        bfr[n][0] = *(const s16x8*)(rp + (((0*4 + lq) ^ xr) << 4));             \
        bfr[n][1] = *(const s16x8*)(rp + (((1*4 + lq) ^ xr) << 4)); }           \
      _Pragma("unroll") for (int m = 0; m < 4; ++m)                             \
      _Pragma("unroll") for (int n = 0; n < 4; ++n) {                           \
        acc[m][n] = __builtin_amdgcn_mfma_f32_16x16x32_bf16(af[m][0], bfr[n][0], acc[m][n], 0, 0, 0); \
        acc[m][n] = __builtin_amdgcn_mfma_f32_16x16x32_bf16(af[m][1], bfr[n][1], acc[m][n], 0, 0, 0); }}

    STG(A0, B0, 0);
    __syncthreads();
    STG(A1, B1, 64);
    CMP(A0, B0);
    __syncthreads();
    STG(A0, B0, 128);
    CMP(A1, B1);
    __syncthreads();
    STG(A1, B1, 192);
    CMP(A0, B0);
    __syncthreads();
    CMP(A1, B1);
#undef STG
#undef CMP
}

// ---------------------------------------------------------------------------
// K1 (fused, R6-verified): grid (32 n-tiles, 4 types, 16 batches)
//  type 0/1: q m-tile 0/128, original orientation -> softmax-over-d -> qT
//  type 2/3: kv head-group g: TRANSPOSED orientation (A=xT rows=n, B=w rows).
//    GEMM k[128n][128col] -> exp->bf16 regs + Z; GEMM v; LDS-transpose both
//    (n becomes MFMA K-dim); 16 MFMA/wave (1 head/wave) -> ctx partials.
//    k/v never touch HBM.
// ---------------------------------------------------------------------------
__global__ __launch_bounds__(256, 2)
void qkv_fused(const unsigned short* __restrict__ wb,
               const unsigned short* __restrict__ xT,
               unsigned short* __restrict__ qT,
               float* __restrict__ ctx_part,
               float* __restrict__ z_part)
{
    __shared__ __align__(16) char smem[65536];
    const int nt = blockIdx.x;
    const int ty = blockIdx.y;
    const int b  = blockIdx.z;
    const int t = threadIdx.x;
    const int lane = t & 63, w = t >> 6;
    const int lr = lane & 15, lq = lane >> 4;
    const int wr = (w >> 1) * 64, wc = (w & 1) * 64;
    const int n0 = nt * 128;

    if (ty < 2) {
        // ---------------- q block (R5-proven path) ----------------
        const int m0 = ty * 128;
        const unsigned short* Bb = xT + (size_t)b * NN * 256;
        f32x4 acc[4][4] = {};
        gemm_core64(wb, Bb, m0, n0, smem, acc);

        __syncthreads();
        unsigned short (*qs)[136] = (unsigned short (*)[136])smem;
#pragma unroll
        for (int n = 0; n < 4; ++n) {
            const int col = wc + n * 16 + lr;
#pragma unroll
            for (int hp = 0; hp < 2; ++hp) {
                float mx = -1e30f;
#pragma unroll
                for (int u = 0; u < 2; ++u)
#pragma unroll
                    for (int r = 0; r < 4; ++r)
                        mx = fmaxf(mx, acc[hp * 2 + u][n][r]);
                mx = fmaxf(mx, __shfl_xor(mx, 16));
                mx = fmaxf(mx, __shfl_xor(mx, 32));
                float er[2][4];
                float s = 0.f;
#pragma unroll
                for (int u = 0; u < 2; ++u)
#pragma unroll
                    for (int r = 0; r < 4; ++r) {
                        er[u][r] = __expf(acc[hp * 2 + u][n][r] - mx);
                        s += er[u][r];
                    }
                s += __shfl_xor(s, 16);
                s += __shfl_xor(s, 32);
                const float inv = QSCALE / s;
#pragma unroll
                for (int u = 0; u < 2; ++u) {
                    ushort4 pk;
                    pk.x = f2bf(er[u][0] * inv);
                    pk.y = f2bf(er[u][1] * inv);
                    pk.z = f2bf(er[u][2] * inv);
                    pk.w = f2bf(er[u][3] * inv);
                    *(ushort4*)&qs[col][wr + (hp * 2 + u) * 16 + lq * 4] = pk;
                }
            }
        }
        __syncthreads();
        const int nl = t >> 1, half = t & 1;
        const unsigned short* src = &qs[nl][half * 64];
        unsigned short* dst = qT + ((size_t)b * NN + n0 + nl) * 256 + m0 + half * 64;
#pragma unroll
        for (int i = 0; i < 8; ++i)
            *(s16x8*)(dst + i * 8) = *(const s16x8*)(src + i * 8);
    } else {
        // ---------------- kv block: transposed orientation ----------------
        const int g = ty - 2;                      // head group (heads 4g..4g+3)
        const unsigned short* An = xT + ((size_t)b * NN + (size_t)n0) * 256;

        // GEMM1: k^T tile [128 n][128 kcol]
        f32x4 acc[4][4] = {};
        gemm_core64(An, wb, 0, 256 + g * 128, smem, acc);

        // exp -> bf16 regs; Z partials (sum over n = rows)
        unsigned int ekpk[4][4][2];
        float zl[4] = {0.f, 0.f, 0.f, 0.f};
#pragma unroll
        for (int m = 0; m < 4; ++m)
#pragma unroll
            for (int nn = 0; nn < 4; ++nn) {
                const unsigned short u0 = f2bf(__expf(acc[m][nn][0]));
                const unsigned short u1 = f2bf(__expf(acc[m][nn][1]));
                const unsigned short u2 = f2bf(__expf(acc[m][nn][2]));
                const unsigned short u3 = f2bf(__expf(acc[m][nn][3]));
                zl[nn] += bf2f(u0) + bf2f(u1) + bf2f(u2) + bf2f(u3);
                ekpk[m][nn][0] = (unsigned int)u0 | ((unsigned int)u1 << 16);
                ekpk[m][nn][1] = (unsigned int)u2 | ((unsigned int)u3 << 16);
            }
#pragma unroll
        for (int nn = 0; nn < 4; ++nn) {
            zl[nn] += __shfl_xor(zl[nn], 16);
            zl[nn] += __shfl_xor(zl[nn], 32);
        }
        const float zv = (lq == 0) ? zl[0] : (lq == 1) ? zl[1] : (lq == 2) ? zl[2] : zl[3];
        z_part[((((size_t)(b * 32 + nt)) * 2 + g) * 2 + (w >> 1)) * 128 + wc + lane] = zv;

        // GEMM2: v^T tile [128 n][128 vcol]
#pragma unroll
        for (int m = 0; m < 4; ++m)
#pragma unroll
            for (int nn = 0; nn < 4; ++nn) acc[m][nn] = (f32x4){0.f, 0.f, 0.f, 0.f};
        gemm_core64(An, wb, 0, 512 + g * 128, smem, acc);

        // LDS transpose: ekT [col][n] at 0, vT [col][n] at 32K (XOR-swizzled)
        __syncthreads();
#pragma unroll
        for (int m = 0; m < 4; ++m)
#pragma unroll
            for (int nn = 0; nn < 4; ++nn) {
                const int col = wc + nn * 16 + lr;
                const int swz = (col & 7) << 4;
                const int rowb = (wr + m * 16 + lq * 4) * 2;   // row byte base (mult of 8)
                *(unsigned int*)(smem + ((col * 256 + rowb) ^ swz))       = ekpk[m][nn][0];
                *(unsigned int*)(smem + ((col * 256 + rowb + 4) ^ swz))   = ekpk[m][nn][1];
                const unsigned int vp0 = (unsigned int)f2bf(acc[m][nn][0])
                                       | ((unsigned int)f2bf(acc[m][nn][1]) << 16);
                const unsigned int vp1 = (unsigned int)f2bf(acc[m][nn][2])
                                       | ((unsigned int)f2bf(acc[m][nn][3]) << 16);
                *(unsigned int*)(smem + 32768 + ((col * 256 + rowb) ^ swz))     = vp0;
                *(unsigned int*)(smem + 32768 + ((col * 256 + rowb + 4) ^ swz)) = vp1;
            }
        __syncthreads();

        // context MFMA: wave w owns head w. C[d][e] = sum_n ekT[d][n] vT[e][n]
        f32x4 cacc[2][2] = {};
#pragma unroll
        for (int ks = 0; ks < 4; ++ks) {
            s16x8 af[2], bfv[2];
#pragma unroll
            for (int dt = 0; dt < 2; ++dt) {
                const int drow = w * 32 + dt * 16 + lr;
                af[dt] = *(const s16x8*)(smem +
                    ((drow * 256 + ks * 64 + lq * 16) ^ ((drow & 7) << 4)));
            }
#pragma unroll
            for (int et = 0; et < 2; ++et) {
                const int erow = w * 32 + et * 16 + lr;
                bfv[et] = *(const s16x8*)(smem + 32768 +
                    ((erow * 256 + ks * 64 + lq * 16) ^ ((erow & 7) << 4)));
            }
#pragma unroll
            for (int dt = 0; dt < 2; ++dt)
#pragma unroll
                for (int et = 0; et < 2; ++et)
                    cacc[dt][et] = __builtin_amdgcn_mfma_f32_16x16x32_bf16(
                        af[dt], bfv[et], cacc[dt][et], 0, 0, 0);
        }
        float* cp = ctx_part + ((((size_t)(b * 32 + nt)) * 2 + g) * 4 + w) * 1024;
#pragma unroll
        for (int dt = 0; dt < 2; ++dt)
#pragma unroll
            for (int et = 0; et < 2; ++et)
#pragma unroll
                for (int r = 0; r < 4; ++r)
                    cp[(dt * 16 + lq * 4 + r) * 32 + et * 16 + lr] = cacc[dt][et][r];
    }
}

// ---------------------------------------------------------------------------
// make_m: reduce 32 n-tile ctx partials + Z, fold w_out -> Mmat bf16
// ---------------------------------------------------------------------------
__global__ __launch_bounds__(256)
void make_m(const float* __restrict__ ctx_part, const float* __restrict__ z_part,
            const float* __restrict__ w_out, unsigned short* __restrict__ Mmat)
{
    const int h = blockIdx.x, b = blockIdx.y;
    const int g = h >> 2, hh = h & 3;
    const int t = threadIdx.x;
    __shared__ float ctx[32][33];
    __shared__ float zinv[32];

    for (int c = t; c < 1024; c += 256) {
        float s = 0.f;
#pragma unroll 8
        for (int nt = 0; nt < 32; ++nt)
            s += ctx_part[((((size_t)(b * 32 + nt)) * 2 + g) * 4 + hh) * 1024 + c];
        ctx[c >> 5][c & 31] = s;
    }
    if (t < 32) {
        float z = 0.f;
#pragma unroll 8
        for (int nt = 0; nt < 32; ++nt) {
            const size_t base = (((size_t)(b * 32 + nt)) * 2 + g) * 2;
            z += z_part[(base + 0) * 128 + hh * 32 + t];
            z += z_part[(base + 1) * 128 + hh * 32 + t];
        }
        zinv[t] = 1.f / z;
    }
    __syncthreads();

    const int o = t;
    float wrow[32];
#pragma unroll
    for (int e = 0; e < 32; ++e)
        wrow[e] = w_out[(size_t)o * 256 + h * 32 + e];
#pragma unroll 4
    for (int d = 0; d < 32; ++d) {
        float s = 0.f;
#pragma unroll
        for (int e = 0; e < 32; ++e)
            s = fmaf(wrow[e], ctx[d][e], s);
        Mmat[((size_t)b * 256 + o) * 256 + h * 32 + d] = f2bf(s * zinv[d]);
    }
}

// ---------------------------------------------------------------------------
// K5: out = Mmat @ q + bias (f32), LDS-transposed coalesced epilogue (R5/R6)
// ---------------------------------------------------------------------------
__global__ __launch_bounds__(256, 2)
void gemm_out(const unsigned short* __restrict__ Mmat,
              const unsigned short* __restrict__ qT,
              float* __restrict__ out, const float* __restrict__ bias)
{
    __shared__ __align__(16) char smem[65536];
    const int bz = blockIdx.z;
    const int m0 = blockIdx.y * 128, n0 = blockIdx.x * 128;
    const unsigned short* Ab = Mmat + (size_t)bz * 256 * 256;
    const unsigned short* Bb = qT + (size_t)bz * NN * 256;

    f32x4 acc[4][4] = {};
    gemm_core64(Ab, Bb, m0, n0, smem, acc);

    const int t = threadIdx.x;
    const int lane = t & 63, w = t >> 6;
    const int lr = lane & 15, lq = lane >> 4;
    const int wr = (w >> 1) * 64, wc = (w & 1) * 64;

    __syncthreads();
#pragma unroll
    for (int m = 0; m < 4; ++m)
#pragma unroll
        for (int r = 0; r < 4; ++r) {
            const int row = wr + m * 16 + lq * 4 + r;
            const float bv = bias[m0 + row];
            const int rb = row * 512;
            const int xs = (row & 7) << 4;
#pragma unroll
            for (int n = 0; n < 4; ++n) {
                const int col = wc + n * 16 + lr;
                *(float*)(smem + rb + ((col * 4) ^ xs)) = acc[m][n][r] + bv;
            }
        }
    __syncthreads();

    float* Yb = out + (size_t)bz * CIN * NN;
#pragma unroll
    for (int p = 0; p < 8; ++p) {
        const int row = p * 16 + (t >> 4);
        const int rb = row * 512;
        const int xs = (row & 7) << 4;
        const int cb = (t & 15) * 32;
        const float4 v0 = *(const float4*)(smem + rb + ((cb + 0) ^ xs));
        const float4 v1 = *(const float4*)(smem + rb + ((cb + 16) ^ xs));
        float* dst = Yb + (size_t)(m0 + row) * NN + n0 + (t & 15) * 8;
        *(float4*)dst = v0;
        *(float4*)(dst + 4) = v1;
    }
}

// ---------------------------------------------------------------------------
extern "C" void kernel_launch(void* const* d_in, const int* in_sizes, int n_in,
                              void* d_out, int out_size, void* d_ws, size_t ws_size,
                              hipStream_t stream)
{
    const float* x     = (const float*)d_in[0];
    const float* w_qkv = (const float*)d_in[1];
    const float* w_out = (const float*)d_in[2];
    const float* b_out = (const float*)d_in[3];
    float* out = (float*)d_out;

    char* ws = (char*)d_ws;
    size_t off = 0;
    unsigned short* xT  = (unsigned short*)(ws + off);  off += (size_t)NBATCH * NN * CIN * 2;          // 32 MiB
    unsigned short* qT  = (unsigned short*)(ws + off);  off += (size_t)NBATCH * NN * CIN * 2;          // 32 MiB
    float* ctx_part     = (float*)(ws + off);           off += (size_t)NBATCH * 32 * 2 * 4 * 1024 * 4; // 16 MiB
    float* z_part       = (float*)(ws + off);           off += (size_t)NBATCH * 32 * 2 * 2 * 128 * 4;  // 1 MiB
    unsigned short* Mmat= (unsigned short*)(ws + off);  off += (size_t)NBATCH * 256 * 256 * 2;         // 2 MiB
    unsigned short* wb  = (unsigned short*)(ws + off);  off += (size_t)CQKV * CIN * 2;

    // K0 (merged): transpose+cast x; cast w_qkv (z == NBATCH slice)
    prep<<<dim3(NN / 64, CIN / 64, NBATCH + 1), 256, 0, stream>>>(x, xT, w_qkv, wb);

    // K1 (fused): q -> qT (softmax); k/v -> ctx/z partials, never touching HBM
    qkv_fused<<<dim3(32, 4, NBATCH), 256, 0, stream>>>(wb, xT, qT, ctx_part, z_part);

    // K4: Mmat = fold(w_out, normalized context)
    make_m<<<dim3(8, NBATCH), 256, 0, stream>>>(ctx_part, z_part, w_out, Mmat);

    // K5: out = Mmat @ q + b_out
    gemm_out<<<dim3(32, 2, NBATCH), 256, 0, stream>>>(Mmat, qT, out, b_out);
}